// Round 12
// baseline (152.365 us; speedup 1.0000x reference)
//
#include <hip/hip_runtime.h>
#include <hip/hip_bf16.h>
#include <math.h>

#define BATCH 4096
#define DIM   2048
#define INV_T 2.0f   // 1 / TEMPERATURE, TEMPERATURE = 0.5

#define BM 128
#define BN 128

typedef float floatx4 __attribute__((ext_vector_type(4)));
typedef int   intx4   __attribute__((ext_vector_type(4)));
typedef int   intx8   __attribute__((ext_vector_type(8)));

static __device__ __forceinline__ void gld_lds16(const void* g, void* l) {
  __builtin_amdgcn_global_load_lds(
      (const __attribute__((address_space(1))) void*)g,
      (__attribute__((address_space(3))) void*)l, 16, 0, 0);
}

static __device__ __forceinline__ intx8 comb8(intx4 lo, intx4 hi) {
  intx8 r;
  r[0] = lo[0]; r[1] = lo[1]; r[2] = lo[2]; r[3] = lo[3];
  r[4] = hi[0]; r[5] = hi[1]; r[6] = hi[2]; r[7] = hi[3];
  return r;
}

// ---------------------------------------------------------------------------
// Kernel 1: per-row log-softmax prep. Wave-per-row, NO barriers. (R15 verbatim
// — harness-verified.) Row-major fp8 outputs; single exp pass; zeroes rowsum
// and the gemm completion counter each iteration (graph-replay safe).
// ---------------------------------------------------------------------------
__global__ __launch_bounds__(256) void prep_kernel(
    const float* __restrict__ ci, const float* __restrict__ cj,
    unsigned char* __restrict__ Li8, unsigned char* __restrict__ Qb8,
    float* __restrict__ hneg, float* __restrict__ isc,
    float* __restrict__ rowsum, unsigned* __restrict__ cnt)
{
  const int lane = threadIdx.x & 63;
  const int wave = threadIdx.x >> 6;
  const int row = blockIdx.x * 4 + wave;
  const bool isj = row >= BATCH;
  const int r = isj ? row - BATCH : row;
  const float* __restrict__ src = (isj ? cj : ci) + (size_t)r * DIM;

  // 32 elements per lane: float4 chunks at [i*64 + lane], i = 0..7
  float v[32];
  #pragma unroll
  for (int i = 0; i < 8; ++i) {
    float4 t = ((const float4*)src)[i * 64 + lane];
    v[i * 4 + 0] = t.x; v[i * 4 + 1] = t.y;
    v[i * 4 + 2] = t.z; v[i * 4 + 3] = t.w;
  }

  // wave max
  float m = v[0];
  #pragma unroll
  for (int i = 1; i < 32; ++i) m = fmaxf(m, v[i]);
  #pragma unroll
  for (int off = 32; off >= 1; off >>= 1) m = fmaxf(m, __shfl_xor(m, off));

  // wave sum of exp(v - m); keep e for the Q pass (single exp pass)
  float e[32];
  float s = 0.f;
  #pragma unroll
  for (int i = 0; i < 32; ++i) { e[i] = __expf(v[i] - m); s += e[i]; }
  #pragma unroll
  for (int off = 32; off >= 1; off >>= 1) s += __shfl_xor(s, off);
  const float ls = m + __logf(s);          // logsumexp of row
  const float inv_s = 1.0f / s;

  // per-row pow2 scale for Q rows: Qmax = exp(m-ls) = 1/s; Qmax*2^t in [128,256)
  float scale = 1.f;
  int t = 0;
  if (isj) {
    const int be = (int)((__float_as_uint(inv_s) >> 23) & 0xff);
    t = 134 - be;
    scale = __uint_as_float((unsigned)(t + 127) << 23);
  }

  unsigned char* dst = (isj ? Qb8 : Li8) + (size_t)r * DIM;
  float h = 0.f;
  #pragma unroll
  for (int i = 0; i < 8; ++i) {
    float f[4];
    #pragma unroll
    for (int j = 0; j < 4; ++j) {
      const float li = v[i * 4 + j] - ls;  // log_softmax element
      if (isj) {
        const float q = e[i * 4 + j] * inv_s;  // exact softmax element
        h += q * li;                       // negative entropy (fp32, exact Q)
        f[j] = q * scale;
      } else {
        f[j] = li;
      }
    }
    int w = __builtin_amdgcn_cvt_pk_fp8_f32(f[0], f[1], 0, false);
    w = __builtin_amdgcn_cvt_pk_fp8_f32(f[2], f[3], w, true);
    ((int*)dst)[i * 64 + lane] = w;        // bytes (i*256 + lane*4) ..+3
  }

  if (isj) {
    #pragma unroll
    for (int off = 32; off >= 1; off >>= 1) h += __shfl_xor(h, off);
    if (lane == 0) {
      hneg[r] = h;
      isc[r] = __uint_as_float((unsigned)(127 - t) << 23);  // 2^-t
      rowsum[r] = 0.f;
    }
  }
  if (row == 0 && lane == 0) cnt[0] = 0u;  // gemm last-block counter
}

// ---------------------------------------------------------------------------
// Kernel 2 (R16): cross' = Li8 @ Qb8^T via MX-fp8 MFMA (16x16x128).
// Five schedules pinned at ~53-57 us shared ONE trait: a single 512-thread
// block per CU with all 8 waves in one barrier group -> every barrier stalls
// the whole CU (convoy). Register-based de-convoy attempts all spilled at
// the VGPR+AGPR <= 256/wave law. R16 de-convoys with ZERO extra per-wave
// registers: 128x128 tile, 4 waves, 2 INDEPENDENT blocks/CU (LDS 64 KB each)
// -> while one block sits at its barrier, the other's waves issue MFMA/LDS.
// acc = 64 AGPR/wave -> ~192 VGPR headroom at 2 waves/SIMD, so all 8
// fragments (af[4]+bf[4], 64 regs) load up-front and the 16 MFMAs run as
// one progressively-lgkm-gated burst. Counted vmcnt(8) per tile (T4);
// fused finalize kept (counter 1023). Epilogue = R13's verified 64x64 form.
// ---------------------------------------------------------------------------
__global__ __launch_bounds__(256, 2) void gemm_lse_kernel(
    const unsigned char* __restrict__ Li8, const unsigned char* __restrict__ Qb8,
    const float* __restrict__ hneg, const float* __restrict__ isc,
    float* __restrict__ rowsum, float* __restrict__ diag,
    unsigned* __restrict__ cnt, float* __restrict__ out)
{
  // 2 dbuf x (A 128x128 + B 128x128) fp8 = 64 KB -> 2 blocks/CU
  __shared__ __attribute__((aligned(16))) unsigned char As_[2][BM * 128];
  __shared__ __attribute__((aligned(16))) unsigned char Bs_[2][BN * 128];

  const int tid  = threadIdx.x;
  // XCD-aware bijective map: 1024 blocks over a 32x32 tile grid; xcd = lin&7
  // owns a full-height 4-wide bx band (by = sq&31, bx = xcd*4 + sq>>5).
  const int lin = blockIdx.x;
  const int xc  = lin & 7;
  const int sq  = lin >> 3;                // 0..127
  const int by  = sq & 31;
  const int bx  = xc * 4 + (sq >> 5);

  const int lane = tid & 63;
  const int wave = tid >> 6;               // 0..3
  const int ww   = wave >> 1;              // 0..1 -> row band ww*64
  const int wc   = wave & 1;               // 0..1 -> col band wc*64

  // staging: 1024 16B-chunks per operand-tile; thread t does chunks t+256*s.
  // LDS chunk p holds global chunk (row = p>>3, cb = (p&7) ^ (row&7)) —
  // same XOR involution as R9 (row stride is still 128 B = 8 chunks).
  int soff[4];
  #pragma unroll
  for (int s = 0; s < 4; ++s) {
    const int p = tid + 256 * s;
    const int row = p >> 3;
    const int cbg = (p & 7) ^ (row & 7);
    soff[s] = row * DIM + cbg * 16;
  }
  const unsigned char* Abase = Li8 + (size_t)(by * BM) * DIM;
  const unsigned char* Bbase = Qb8 + (size_t)(bx * BN) * DIM;

  const int rl = lane & 15;                // m/n within frag; col within C/D
  const int q  = lane >> 4;                // k-quad: k in [q*32, q*32+32)
  const int sw = rl & 7;                   // XOR swizzle key (row & 7)

  floatx4 acc[4][4];                       // 64 AGPRs: wave tile 64x64
  const floatx4 z = {0.f, 0.f, 0.f, 0.f};
  #pragma unroll
  for (int mt = 0; mt < 4; ++mt)
    #pragma unroll
    for (int nt = 0; nt < 4; ++nt) acc[mt][nt] = z;

  // prologue: stage K-tile 0 into buffer 0 (8 loads/thread)
  #pragma unroll
  for (int s = 0; s < 4; ++s) {
    gld_lds16(Abase + soff[s], &As_[0][0] + (tid + 256 * s) * 16);
    gld_lds16(Bbase + soff[s], &Bs_[0][0] + (tid + 256 * s) * 16);
  }

  for (int t = 0; t < 16; ++t) {
    const int cur = t & 1;
    const unsigned char* Ab = &As_[cur][0];
    const unsigned char* Bb = &Bs_[cur][0];

    // issue next tile's 8 staging loads, then counted wait: vmcnt(8) = tile
    // t's loads have landed, t+1's 8 stay in flight across the barrier (T4).
    if (t < 15) {
      unsigned char* An = &As_[cur ^ 1][0];
      unsigned char* Bn = &Bs_[cur ^ 1][0];
      const int kn = (t + 1) * 128;
      #pragma unroll
      for (int s = 0; s < 4; ++s) {
        gld_lds16(Abase + soff[s] + kn, An + (tid + 256 * s) * 16);
        gld_lds16(Bbase + soff[s] + kn, Bn + (tid + 256 * s) * 16);
      }
      asm volatile("s_waitcnt vmcnt(8)" ::: "memory");
    } else {
      asm volatile("s_waitcnt vmcnt(0)" ::: "memory");
    }
    asm volatile("s_barrier" ::: "memory");

    // ---- all 16 ds_reads up front (af/bf interleaved so the first MFMAs
    // gate early), then one 16-MFMA burst with progressive lgkmcnt ----
    intx8 af[4], bf[4];
    #pragma unroll
    for (int i = 0; i < 4; ++i) {
      const int ra = ww * 64 + i * 16 + rl;
      const int a0 = ra * 8 + ((2 * q) ^ sw);
      const int a1 = ra * 8 + ((2 * q + 1) ^ sw);
      af[i] = comb8(*(const intx4*)(Ab + a0 * 16),
                    *(const intx4*)(Ab + a1 * 16));
      const int rb = wc * 64 + i * 16 + rl;
      const int b0 = rb * 8 + ((2 * q) ^ sw);
      const int b1 = rb * 8 + ((2 * q + 1) ^ sw);
      bf[i] = comb8(*(const intx4*)(Bb + b0 * 16),
                    *(const intx4*)(Bb + b1 * 16));
    }
    __builtin_amdgcn_s_setprio(1);
    #pragma unroll
    for (int mt = 0; mt < 4; ++mt)
      #pragma unroll
      for (int nt = 0; nt < 4; ++nt)
        acc[mt][nt] = __builtin_amdgcn_mfma_scale_f32_16x16x128_f8f6f4(
            af[mt], bf[nt], acc[mt][nt],
            0, 0,            // cbsz = fp8(e4m3), blgp = fp8(e4m3)
            0, 127,          // scale A: 1.0
            0, 127);         // scale B: 1.0
    __builtin_amdgcn_s_setprio(0);

    // end barrier: all waves done reading buf[cur] before t+1 stages into it
    asm volatile("s_barrier" ::: "memory");
  }

  // ---- epilogue. C/D layout: col = lane&15, row = (lane>>4)*4 + reg ----
  const int col0 = bx * BN + wc * 64 + rl;
  float hn[4], sc[4];
  #pragma unroll
  for (int nt = 0; nt < 4; ++nt) {
    hn[nt] = hneg[col0 + nt * 16];
    sc[nt] = isc[col0 + nt * 16];
  }
  const int row0 = by * BM + ww * 64 + (q << 2);

  // diag: wave covers rows [ww*64,+64) x cols [wc*64,+64); diagonal iff
  // bx==by && ww==wc; then local row==col => mt==nt, q==rl>>2, rr==rl&3.
  // acc indices compile-time (rule #20); runtime tests in the predicate.
  // atomicExch (device-scope) so the finalize block sees it across XCDs.
  if (bx == by && ww == wc && q == (rl >> 2)) {
    #pragma unroll
    for (int nt = 0; nt < 4; ++nt) {
      #pragma unroll
      for (int rr = 0; rr < 4; ++rr) {
        if ((rl & 3) == rr)
          atomicExch(&diag[bx * BN + wc * 64 + nt * 16 + rl],
                     acc[nt][nt][rr] * sc[nt]);
      }
    }
  }

  #pragma unroll
  for (int mt = 0; mt < 4; ++mt) {
    #pragma unroll
    for (int rr = 0; rr < 4; ++rr) {
      float p = 0.f;
      #pragma unroll
      for (int nt = 0; nt < 4; ++nt)
        p += __expf(INV_T * (acc[mt][nt][rr] * sc[nt] - hn[nt]));
      // reduce across 16 cols (lane&15 group)
      p += __shfl_xor(p, 1);
      p += __shfl_xor(p, 2);
      p += __shfl_xor(p, 4);
      p += __shfl_xor(p, 8);
      if (rl == 0)
        atomicAdd(&rowsum[row0 + mt * 16 + rr], p);
    }
  }

  // ---- fused finalize: last block to finish computes the loss ----
  __shared__ unsigned last_flag;
  __syncthreads();                         // all threads' atomics issued
  if (tid == 0) {
    __threadfence();                       // make them device-visible
    last_flag = (atomicAdd(cnt, 1u) == 1023u);
  }
  __syncthreads();
  if (last_flag) {
    float c = 0.f;
    #pragma unroll
    for (int j = 0; j < 16; ++j) {
      const int i = tid + j * 256;
      c += __logf(rowsum[i]) - INV_T * (diag[i] - hneg[i]);
    }
    #pragma unroll
    for (int off = 32; off >= 1; off >>= 1) c += __shfl_xor(c, off);
    __shared__ float red[4];
    if (lane == 0) red[wave] = c;
    __syncthreads();
    if (tid == 0)
      out[0] = (red[0] + red[1] + red[2] + red[3]) * (1.0f / BATCH);
  }
}

// ---------------------------------------------------------------------------
extern "C" void kernel_launch(void* const* d_in, const int* in_sizes, int n_in,
                              void* d_out, int out_size, void* d_ws, size_t ws_size,
                              hipStream_t stream) {
  const float* ci = (const float*)d_in[0];
  const float* cj = (const float*)d_in[1];
  float* out = (float*)d_out;

  // ws: Li8 u8[B*D] | Qb8 u8[B*D] | hneg f32[B] | isc f32[B] | rowsum f32[B]
  //     | diag f32[B] | cnt u32[1]
  unsigned char* Li8 = (unsigned char*)d_ws;
  unsigned char* Qb8 = Li8 + (size_t)BATCH * DIM;
  float* hneg   = (float*)(Qb8 + (size_t)BATCH * DIM);
  float* isc    = hneg + BATCH;
  float* rowsum = isc + BATCH;
  float* diag   = rowsum + BATCH;
  unsigned* cnt = (unsigned*)(diag + BATCH);

  prep_kernel<<<2 * BATCH / 4, 256, 0, stream>>>(ci, cj, Li8, Qb8, hneg, isc, rowsum, cnt);
  gemm_lse_kernel<<<(BATCH / BM) * (BATCH / BN), 256, 0, stream>>>(
      Li8, Qb8, hneg, isc, rowsum, diag, cnt, out);
}

// Round 13
// 145.677 us; speedup vs baseline: 1.0459x; 1.0459x over previous
//
#include <hip/hip_runtime.h>
#include <hip/hip_bf16.h>
#include <math.h>

#define BATCH 4096
#define DIM   2048
#define INV_T 2.0f   // 1 / TEMPERATURE, TEMPERATURE = 0.5

#define BM 256
#define BN 256

typedef float floatx4 __attribute__((ext_vector_type(4)));
typedef int   intx4   __attribute__((ext_vector_type(4)));
typedef int   intx8   __attribute__((ext_vector_type(8)));

static __device__ __forceinline__ void gld_lds16(const void* g, void* l) {
  __builtin_amdgcn_global_load_lds(
      (const __attribute__((address_space(1))) void*)g,
      (__attribute__((address_space(3))) void*)l, 16, 0, 0);
}

// build an 8-dword fragment from two 16B LDS reads via union halves (gives
// regalloc the chance to target the tuple's halves directly, vs comb8's
// elementwise copy which showed up as v_mov pressure in VALUBusy)
static __device__ __forceinline__ intx8 ld_frag(const void* p0, const void* p1) {
  union { intx8 v; intx4 q[2]; } u;
  u.q[0] = *(const intx4*)p0;
  u.q[1] = *(const intx4*)p1;
  return u.v;
}

// ---------------------------------------------------------------------------
// Kernel 1: per-row log-softmax prep. Wave-per-row, NO barriers. (R15 verbatim
// — harness-verified.) Row-major fp8 outputs; single exp pass; zeroes rowsum
// and the gemm completion counter each iteration (graph-replay safe).
// ---------------------------------------------------------------------------
__global__ __launch_bounds__(256) void prep_kernel(
    const float* __restrict__ ci, const float* __restrict__ cj,
    unsigned char* __restrict__ Li8, unsigned char* __restrict__ Qb8,
    float* __restrict__ hneg, float* __restrict__ isc,
    float* __restrict__ rowsum, unsigned* __restrict__ cnt)
{
  const int lane = threadIdx.x & 63;
  const int wave = threadIdx.x >> 6;
  const int row = blockIdx.x * 4 + wave;
  const bool isj = row >= BATCH;
  const int r = isj ? row - BATCH : row;
  const float* __restrict__ src = (isj ? cj : ci) + (size_t)r * DIM;

  // 32 elements per lane: float4 chunks at [i*64 + lane], i = 0..7
  float v[32];
  #pragma unroll
  for (int i = 0; i < 8; ++i) {
    float4 t = ((const float4*)src)[i * 64 + lane];
    v[i * 4 + 0] = t.x; v[i * 4 + 1] = t.y;
    v[i * 4 + 2] = t.z; v[i * 4 + 3] = t.w;
  }

  // wave max
  float m = v[0];
  #pragma unroll
  for (int i = 1; i < 32; ++i) m = fmaxf(m, v[i]);
  #pragma unroll
  for (int off = 32; off >= 1; off >>= 1) m = fmaxf(m, __shfl_xor(m, off));

  // wave sum of exp(v - m); keep e for the Q pass (single exp pass)
  float e[32];
  float s = 0.f;
  #pragma unroll
  for (int i = 0; i < 32; ++i) { e[i] = __expf(v[i] - m); s += e[i]; }
  #pragma unroll
  for (int off = 32; off >= 1; off >>= 1) s += __shfl_xor(s, off);
  const float ls = m + __logf(s);          // logsumexp of row
  const float inv_s = 1.0f / s;

  // per-row pow2 scale for Q rows: Qmax = exp(m-ls) = 1/s; Qmax*2^t in [128,256)
  float scale = 1.f;
  int t = 0;
  if (isj) {
    const int be = (int)((__float_as_uint(inv_s) >> 23) & 0xff);
    t = 134 - be;
    scale = __uint_as_float((unsigned)(t + 127) << 23);
  }

  unsigned char* dst = (isj ? Qb8 : Li8) + (size_t)r * DIM;
  float h = 0.f;
  #pragma unroll
  for (int i = 0; i < 8; ++i) {
    float f[4];
    #pragma unroll
    for (int j = 0; j < 4; ++j) {
      const float li = v[i * 4 + j] - ls;  // log_softmax element
      if (isj) {
        const float q = e[i * 4 + j] * inv_s;  // exact softmax element
        h += q * li;                       // negative entropy (fp32, exact Q)
        f[j] = q * scale;
      } else {
        f[j] = li;
      }
    }
    int w = __builtin_amdgcn_cvt_pk_fp8_f32(f[0], f[1], 0, false);
    w = __builtin_amdgcn_cvt_pk_fp8_f32(f[2], f[3], w, true);
    ((int*)dst)[i * 64 + lane] = w;        // bytes (i*256 + lane*4) ..+3
  }

  if (isj) {
    #pragma unroll
    for (int off = 32; off >= 1; off >>= 1) h += __shfl_xor(h, off);
    if (lane == 0) {
      hneg[r] = h;
      isc[r] = __uint_as_float((unsigned)(127 - t) << 23);  // 2^-t
      rowsum[r] = 0.f;
    }
  }
  if (row == 0 && lane == 0) cnt[0] = 0u;  // gemm last-block counter
}

// ---------------------------------------------------------------------------
// Kernel 2 (R17): cross' = Li8 @ Qb8^T via MX-fp8 MFMA (16x16x128).
// Structure = R15/R9 (best measured, no spill). R17 micro-fixes from counters:
//  (a) bank-conflict fix: swizzle key (row&7) was blind to row bit 3 -> lane
//      pairs (rl, rl+8) hit the same 4 banks every ds_read_b128
//      (SQ_LDS_BANK_CONFLICT = 3.145M = 768 cy/tile/CU). New key
//      (row ^ (row>>3)) & 7 on BOTH sides (write cbg + read addr) — still a
//      per-row bijection, involution rule intact.
//  (b) ld_frag union halves instead of comb8 elementwise copy (v_mov cut).
//  (c) epilogue folded to fmaf + exp2f with precomputed INV_T*log2e scales.
// Fused finalize kept (counter 255).
// ---------------------------------------------------------------------------
__global__ __launch_bounds__(512, 1) void gemm_lse_kernel(
    const unsigned char* __restrict__ Li8, const unsigned char* __restrict__ Qb8,
    const float* __restrict__ hneg, const float* __restrict__ isc,
    float* __restrict__ rowsum, float* __restrict__ diag,
    unsigned* __restrict__ cnt, float* __restrict__ out)
{
  // 2 dbuf x (A 256x128 + B 256x128) fp8 = 128 KB
  __shared__ __attribute__((aligned(16))) unsigned char As_[2][BM * 128];
  __shared__ __attribute__((aligned(16))) unsigned char Bs_[2][BN * 128];

  const int tid  = threadIdx.x;
  // XCD-aware patch mapping: 256 blocks, xcd = lin&7 owns a 4(by) x 8(bx)
  // rectangle of the 16x16 tile grid (bijective).
  const int lin = blockIdx.x;
  const int xc  = lin & 7;
  const int sq  = lin >> 3;                // 0..31
  const int by  = (xc & 3) * 4 + (sq & 3);
  const int bx  = (xc >> 2) * 8 + (sq >> 2);

  const int lane = tid & 63;
  const int wave = tid >> 6;               // 0..7
  const int wm   = wave >> 2;              // 0..1 -> row band wm*128
  const int wn   = wave & 3;               // 0..3 -> col band wn*64

  // staging: 2048 16B-chunks per operand-tile; thread t does chunks t+512*s.
  // LDS chunk p holds global chunk (row = p>>3, cb = (p&7) ^ key(row)),
  // key(row) = (row ^ (row>>3)) & 7  [R17: includes row bit 3].
  int soff[4];
  #pragma unroll
  for (int s = 0; s < 4; ++s) {
    const int p = tid + 512 * s;
    const int row = p >> 3;
    const int cbg = (p & 7) ^ ((row ^ (row >> 3)) & 7);
    soff[s] = row * DIM + cbg * 16;
  }
  const unsigned char* Abase = Li8 + (size_t)(by * BM) * DIM;
  const unsigned char* Bbase = Qb8 + (size_t)(bx * BN) * DIM;

  const int rl = lane & 15;                // m/n within frag; col within C/D
  const int q  = lane >> 4;                // k-quad: k in [q*32, q*32+32)

  floatx4 acc[8][4];
  const floatx4 z = {0.f, 0.f, 0.f, 0.f};
  #pragma unroll
  for (int mt = 0; mt < 8; ++mt)
    #pragma unroll
    for (int nt = 0; nt < 4; ++nt) acc[mt][nt] = z;

  // prologue: stage K-tile 0 into buffer 0 (8 loads/thread)
  #pragma unroll
  for (int s = 0; s < 4; ++s) {
    gld_lds16(Abase + soff[s], &As_[0][0] + (tid + 512 * s) * 16);
    gld_lds16(Bbase + soff[s], &Bs_[0][0] + (tid + 512 * s) * 16);
  }

  for (int t = 0; t < 16; ++t) {
    const int cur = t & 1;
    const unsigned char* Ab = &As_[cur][0];
    const unsigned char* Bb = &Bs_[cur][0];

    // issue ALL of next tile's staging up front (8 loads), then counted wait:
    // vmcnt(8) = everything from tile t has landed, t+1's 8 stay in flight
    // across the barrier (T4).
    if (t < 15) {
      unsigned char* An = &As_[cur ^ 1][0];
      unsigned char* Bn = &Bs_[cur ^ 1][0];
      const int kn = (t + 1) * 128;
      #pragma unroll
      for (int s = 0; s < 4; ++s) {
        gld_lds16(Abase + soff[s] + kn, An + (tid + 512 * s) * 16);
        gld_lds16(Bbase + soff[s] + kn, Bn + (tid + 512 * s) * 16);
      }
      asm volatile("s_waitcnt vmcnt(8)" ::: "memory");
    } else {
      asm volatile("s_waitcnt vmcnt(0)" ::: "memory");
    }
    asm volatile("s_barrier" ::: "memory");

    // ---- compute on buf[cur]: no barriers inside the tile ----
    // B fragments for the whole K-tile (32 VGPRs)
    intx8 bf[4];
    #pragma unroll
    for (int nt = 0; nt < 4; ++nt) {
      const int rb = wn * 64 + nt * 16 + rl;
      const int kB = (rb ^ (rb >> 3)) & 7;
      bf[nt] = ld_frag(Bb + (rb * 8 + ((2 * q) ^ kB)) * 16,
                       Bb + (rb * 8 + ((2 * q + 1) ^ kB)) * 16);
    }
    // A-fragment ping-pong, pipelined one sub-step ahead.
    intx8 af[2];
    {
      const int ra = wm * 128 + rl;
      const int kA = (ra ^ (ra >> 3)) & 7;
      af[0] = ld_frag(Ab + (ra * 8 + ((2 * q) ^ kA)) * 16,
                      Ab + (ra * 8 + ((2 * q + 1) ^ kA)) * 16);
    }
    #pragma unroll
    for (int s = 0; s < 8; ++s) {
      if (s < 7) {
        const int ra = wm * 128 + (s + 1) * 16 + rl;
        const int kA = (ra ^ (ra >> 3)) & 7;
        af[(s + 1) & 1] = ld_frag(Ab + (ra * 8 + ((2 * q) ^ kA)) * 16,
                                  Ab + (ra * 8 + ((2 * q + 1) ^ kA)) * 16);
      }
      __builtin_amdgcn_s_setprio(1);
      #pragma unroll
      for (int nt = 0; nt < 4; ++nt)
        acc[s][nt] = __builtin_amdgcn_mfma_scale_f32_16x16x128_f8f6f4(
            af[s & 1], bf[nt], acc[s][nt],
            0, 0,            // cbsz = fp8(e4m3), blgp = fp8(e4m3)
            0, 127,          // scale A: 1.0
            0, 127);         // scale B: 1.0
      __builtin_amdgcn_s_setprio(0);
    }

    // end barrier: all waves done READING buf[cur] before t+1 stages into it
    asm volatile("s_barrier" ::: "memory");
  }

  // ---- epilogue. C/D layout: col = lane&15, row = (lane>>4)*4 + reg ----
  const int col0 = bx * BN + wn * 64 + rl;
  const float L2E_T = INV_T * 1.4426950408889634f;  // INV_T * log2(e)
  float sc[4], aS[4], bS[4];
  #pragma unroll
  for (int nt = 0; nt < 4; ++nt) {
    const float hnv = hneg[col0 + nt * 16];
    sc[nt] = isc[col0 + nt * 16];
    aS[nt] = L2E_T * sc[nt];               // exp arg = acc*aS + bS
    bS[nt] = -L2E_T * hnv;
  }
  const int row0 = by * BM + wm * 128 + (q << 2);

  // diag: rows wm*128.. overlap cols wn*64.. iff wm == wn>>1; row==col picks
  // mt = (wn&1)*4 + nt, q == rl>>2, reg rr == rl&3. ALL acc indices are
  // compile-time (rule #20); runtime selection lives in the store predicate.
  // atomicExch (device-scope) so the finalize block sees it across XCDs.
  if (bx == by && wm == (wn >> 1) && q == (rl >> 2)) {
    #pragma unroll
    for (int half = 0; half < 2; ++half) {
      #pragma unroll
      for (int nt = 0; nt < 4; ++nt) {
        #pragma unroll
        for (int rr = 0; rr < 4; ++rr) {
          if ((wn & 1) == half && (rl & 3) == rr)
            atomicExch(&diag[bx * BN + wn * 64 + nt * 16 + rl],
                       acc[half * 4 + nt][nt][rr] * sc[nt]);
        }
      }
    }
  }

  #pragma unroll
  for (int mt = 0; mt < 8; ++mt) {
    #pragma unroll
    for (int rr = 0; rr < 4; ++rr) {
      float p = 0.f;
      #pragma unroll
      for (int nt = 0; nt < 4; ++nt)
        p += exp2f(fmaf(acc[mt][nt][rr], aS[nt], bS[nt]));
      // reduce across 16 cols (lane&15 group)
      p += __shfl_xor(p, 1);
      p += __shfl_xor(p, 2);
      p += __shfl_xor(p, 4);
      p += __shfl_xor(p, 8);
      if (rl == 0)
        atomicAdd(&rowsum[row0 + mt * 16 + rr], p);
    }
  }

  // ---- fused finalize: last block to finish computes the loss ----
  __shared__ unsigned last_flag;
  __syncthreads();                         // all threads' atomics issued
  if (tid == 0) {
    __threadfence();                       // make them device-visible
    last_flag = (atomicAdd(cnt, 1u) == 255u);
  }
  __syncthreads();
  if (last_flag) {
    float c = 0.f;
    #pragma unroll
    for (int j = 0; j < 8; ++j) {
      const int i = tid + j * 512;
      c += __logf(rowsum[i]) - INV_T * (diag[i] - hneg[i]);
    }
    #pragma unroll
    for (int off = 32; off >= 1; off >>= 1) c += __shfl_xor(c, off);
    __shared__ float red[8];
    if (lane == 0) red[wave] = c;
    __syncthreads();
    if (tid == 0) {
      float tot = 0.f;
      #pragma unroll
      for (int w = 0; w < 8; ++w) tot += red[w];
      out[0] = tot * (1.0f / BATCH);
    }
  }
}

// ---------------------------------------------------------------------------
extern "C" void kernel_launch(void* const* d_in, const int* in_sizes, int n_in,
                              void* d_out, int out_size, void* d_ws, size_t ws_size,
                              hipStream_t stream) {
  const float* ci = (const float*)d_in[0];
  const float* cj = (const float*)d_in[1];
  float* out = (float*)d_out;

  // ws: Li8 u8[B*D] | Qb8 u8[B*D] | hneg f32[B] | isc f32[B] | rowsum f32[B]
  //     | diag f32[B] | cnt u32[1]
  unsigned char* Li8 = (unsigned char*)d_ws;
  unsigned char* Qb8 = Li8 + (size_t)BATCH * DIM;
  float* hneg   = (float*)(Qb8 + (size_t)BATCH * DIM);
  float* isc    = hneg + BATCH;
  float* rowsum = isc + BATCH;
  float* diag   = rowsum + BATCH;
  unsigned* cnt = (unsigned*)(diag + BATCH);

  prep_kernel<<<2 * BATCH / 4, 256, 0, stream>>>(ci, cj, Li8, Qb8, hneg, isc, rowsum, cnt);
  gemm_lse_kernel<<<(BATCH / BM) * (BATCH / BN), 512, 0, stream>>>(
      Li8, Qb8, hneg, isc, rowsum, diag, cnt, out);
}